// Round 3
// baseline (1108.680 us; speedup 1.0000x reference)
//
#include <hip/hip_runtime.h>

// ---------------------------------------------------------------------------
// MoE LM forward, MI355X round 5.
// Dual-dtype (runtime-sniffed bf16 vs f32 inputs/outputs), f32 accumulation.
// Pipeline: k_sniff -> {k_transph, k_transpose} -> k_embed_pre -> k_scan
//           -> k_ffn -> k_gates -> k_ln -> k_head.
// R5: k_scan: 8-step chunks -- pre prefetched 8-wide into named regs, mem
//     stores batched at chunk end (kills per-step vmcnt(0) store-drain on the
//     single serial wave); dot split into 4 pk-fma chains of depth 8; sm[]
//     written before global store.  headWT transpose -> LDS-tiled coalesced
//     kernel k_transph (was 1M scattered 2-B stores).
// ---------------------------------------------------------------------------

#define VV 16000
#define BB 8
#define TT 1024
#define DD 64
#define FF 256
#define EE 8
#define BT 8192   // B*T

typedef unsigned short u16;
typedef unsigned int   u32;
typedef __attribute__((ext_vector_type(8))) short short8;   // 8 x bf16 (4 VGPR)
typedef __attribute__((ext_vector_type(4))) float f32x4;    // MFMA C/D
typedef __attribute__((ext_vector_type(2))) float f32x2;    // v_pk_fma_f32

__device__ __forceinline__ float bf2f(u16 u) {
    union { u32 i; float f; } v; v.i = ((u32)u) << 16; return v.f;
}
__device__ __forceinline__ u16 f2bf(float f) {  // round-to-nearest-even
    union { float f; u32 i; } v; v.f = f;
    u32 lsb = (v.i >> 16) & 1u;
    return (u16)((v.i + 0x7fffu + lsb) >> 16);
}
__device__ __forceinline__ short8 ld8(const u16* p) { return *(const short8*)p; }
// dual-dtype scalar load: input array is bf16 (isbf=1) or f32 (isbf=0)
__device__ __forceinline__ float ldf(const void* p, int i, int isbf) {
    return isbf ? bf2f(((const u16*)p)[i]) : ((const float*)p)[i];
}

// ---------------------------------------------------------------------------
// K-1: dtype sniffer. 256 samples, majority vote on bf16-plausible exponent.
// ---------------------------------------------------------------------------
__global__ __launch_bounds__(256) void k_sniff(const u32* __restrict__ tblw,
                                               int* __restrict__ flag) {
    __shared__ int c;
    int tid = threadIdx.x;
    if (tid == 0) c = 0;
    __syncthreads();
    u32 u = tblw[tid];
    u32 lo = u & 0xFFFFu;
    u32 e = (lo >> 7) & 0xFFu;
    int hit = ((e >= 0x60u && e <= 0x7Eu) || lo == 0u) ? 1 : 0;
    atomicAdd(&c, hit);
    __syncthreads();
    if (tid == 0) *flag = (c >= 192) ? 1 : 0;
}

// ---------------------------------------------------------------------------
// K0a: headW [64][16000] -> headWT [16000][64] bf16, LDS-tiled 64x64.
//      Coalesced reads (256 B/wave), padded tile (conflict-free), coalesced
//      bf16 writes (128 B/wave).  Grid = 250 (16000/64).
// ---------------------------------------------------------------------------
__global__ __launch_bounds__(256) void k_transph(const void* __restrict__ headW,
                                                 const int* __restrict__ flag,
                                                 u16* __restrict__ headWT) {
    __shared__ float tile[DD][DD + 1];
    int isbf = *flag;
    int v0 = blockIdx.x * 64;
    int tid = threadIdx.x;
    int c = tid & 63, rq = tid >> 6;      // c: lane col, rq: row quarter
#pragma unroll
    for (int i = 0; i < 16; i++) {
        int k = i * 4 + rq;
        tile[k][c] = ldf(headW, k * VV + v0 + c, isbf);
    }
    __syncthreads();
#pragma unroll
    for (int i = 0; i < 16; i++) {
        int v = i * 4 + rq;
        headWT[(v0 + v) * DD + c] = f2bf(tile[c][v]);
    }
}

// ---------------------------------------------------------------------------
// K0b: W1/W2 -> canonical bf16 B^T layout (small: 262K elements).
//   W1T[e][f][d] = W1[e][d][f];  W2T[e][d][f] = W2[e][f][d]
// ---------------------------------------------------------------------------
__global__ __launch_bounds__(256) void k_transpose(const void* __restrict__ W1,
                                                   const void* __restrict__ W2,
                                                   const int* __restrict__ flag,
                                                   u16* __restrict__ W1T,
                                                   u16* __restrict__ W2T) {
    int isbf = *flag;
    int idx = blockIdx.x * 256 + threadIdx.x;   // grid 1024 -> 262144
    if (idx < EE * DD * FF) {
        int e = idx >> 14, r = idx & 16383, d = r >> 8, f = r & 255;
        W1T[e * 16384 + f * DD + d] = f2bf(ldf(W1, idx, isbf));
    } else {
        int j2 = idx - EE * DD * FF;
        int e = j2 >> 14, r = j2 & 16383, f = r >> 6, d = r & 63;
        W2T[e * 16384 + d * FF + f] = f2bf(ldf(W2, j2, isbf));
    }
}

// ---------------------------------------------------------------------------
// K1: gather embeddings (-> canonical bf16 emb) + pre[t][b][:] = emb@Wm + bm.
//     4 threads per token (q = quarter of the 64 output columns).
// ---------------------------------------------------------------------------
__global__ __launch_bounds__(256) void k_embed_pre(const int* __restrict__ x,
                                                   const void* __restrict__ tbl,
                                                   const void* __restrict__ Wm,
                                                   const void* __restrict__ bm,
                                                   const int* __restrict__ flag,
                                                   u16* __restrict__ emb,
                                                   float* __restrict__ pre) {
    __shared__ float sWm[DD * DD];
    __shared__ float sbm[DD];
    int isbf = *flag;
    int tid = threadIdx.x;
    for (int i = tid; i < DD * DD; i += 256) sWm[i] = ldf(Wm, i, isbf);
    if (tid < DD) sbm[tid] = ldf(bm, tid, isbf);
    __syncthreads();

    int gi = blockIdx.x * 256 + tid;           // grid = 128
    int tok = gi >> 2, q = gi & 3;             // 4 threads per token
    int id = x[tok];
    float e[DD];
    if (isbf) {
        const uint4* src = (const uint4*)((const u16*)tbl + id * DD);
        uint4* dst = (uint4*)(emb + tok * DD);
#pragma unroll
        for (int i = 0; i < 8; i++) {
            uint4 v = src[i];
            if ((i >> 1) == q) dst[i] = v;     // each q writes 2 of 8 uint4
            const u16* pu = (const u16*)&v;
#pragma unroll
            for (int j = 0; j < 8; j++) e[i * 8 + j] = bf2f(pu[j]);
        }
    } else {
        const float4* src = (const float4*)((const float*)tbl + id * DD);
        u16* dst = emb + tok * DD;
#pragma unroll
        for (int i = 0; i < 16; i++) {
            float4 v = src[i];
            e[i * 4 + 0] = v.x; e[i * 4 + 1] = v.y;
            e[i * 4 + 2] = v.z; e[i * 4 + 3] = v.w;
            if ((i >> 2) == q) {               // each q writes 4 of 16 pairs
                u32 p0 = (u32)f2bf(v.x) | ((u32)f2bf(v.y) << 16);
                u32 p1 = (u32)f2bf(v.z) | ((u32)f2bf(v.w) << 16);
                ((u32*)dst)[i * 2] = p0;
                ((u32*)dst)[i * 2 + 1] = p1;
            }
        }
    }
    int b = tok >> 10, t = tok & 1023;
    float* prow = pre + (t * BB + b) * DD + q * 16;
#pragma unroll
    for (int j4 = 0; j4 < 4; j4++) {
        int j0 = q * 16 + j4 * 4;
        float a0 = sbm[j0 + 0], a1 = sbm[j0 + 1];
        float a2 = sbm[j0 + 2], a3 = sbm[j0 + 3];
#pragma unroll
        for (int k = 0; k < DD; k++) {
            float ek = e[k];
            float4 wv = *(const float4*)&sWm[k * DD + j0];
            a0 += ek * wv.x; a1 += ek * wv.y;
            a2 += ek * wv.z; a3 += ek * wv.w;
        }
        ((float4*)prow)[j4] = make_float4(a0, a1, a2, a3);
    }
}

// ---------------------------------------------------------------------------
// K2: serial scan. 8 blocks (one per batch row), 1 wave each.
//     lane j owns column j; Um column j in 32 NAMED f32x2 (VGPR-resident).
//     R5 structure: 128 chunks of 8 steps.  Per chunk: prefetch next 8 pre
//     values into named regs, run 8 unrolled steps (LDS roundtrip only on
//     the critical path), store the 8 mem results at chunk end.  This keeps
//     global stores OFF the per-step critical path (one vmcnt wait / 8
//     steps instead of a store-drain per step).
//     Dot = 4 pk-fma chains of depth 8 (sum regrouping only).
// ---------------------------------------------------------------------------
__global__ __launch_bounds__(64, 1) void k_scan(const float* __restrict__ pre,
                                                const void* __restrict__ Um,
                                                const int* __restrict__ flag,
                                                float* __restrict__ mem) {
    int isbf = *flag;
    int b = blockIdx.x, j = threadIdx.x;
    __shared__ float sm[DD];

    f32x2 c0, c1, c2, c3, c4, c5, c6, c7, c8, c9, c10, c11, c12, c13, c14, c15,
          c16, c17, c18, c19, c20, c21, c22, c23, c24, c25, c26, c27, c28, c29,
          c30, c31;
    if (isbf) {
        const u16* up = (const u16*)Um + j;
#define LDU(VAR, I) VAR = (f32x2){bf2f(up[(2 * I) * DD]), bf2f(up[(2 * I + 1) * DD])};
        LDU(c0, 0)  LDU(c1, 1)  LDU(c2, 2)  LDU(c3, 3)
        LDU(c4, 4)  LDU(c5, 5)  LDU(c6, 6)  LDU(c7, 7)
        LDU(c8, 8)  LDU(c9, 9)  LDU(c10, 10) LDU(c11, 11)
        LDU(c12, 12) LDU(c13, 13) LDU(c14, 14) LDU(c15, 15)
        LDU(c16, 16) LDU(c17, 17) LDU(c18, 18) LDU(c19, 19)
        LDU(c20, 20) LDU(c21, 21) LDU(c22, 22) LDU(c23, 23)
        LDU(c24, 24) LDU(c25, 25) LDU(c26, 26) LDU(c27, 27)
        LDU(c28, 28) LDU(c29, 29) LDU(c30, 30) LDU(c31, 31)
#undef LDU
    } else {
        const float* up = (const float*)Um + j;
#define LDU(VAR, I) VAR = (f32x2){up[(2 * I) * DD], up[(2 * I + 1) * DD]};
        LDU(c0, 0)  LDU(c1, 1)  LDU(c2, 2)  LDU(c3, 3)
        LDU(c4, 4)  LDU(c5, 5)  LDU(c6, 6)  LDU(c7, 7)
        LDU(c8, 8)  LDU(c9, 9)  LDU(c10, 10) LDU(c11, 11)
        LDU(c12, 12) LDU(c13, 13) LDU(c14, 14) LDU(c15, 15)
        LDU(c16, 16) LDU(c17, 17) LDU(c18, 18) LDU(c19, 19)
        LDU(c20, 20) LDU(c21, 21) LDU(c22, 22) LDU(c23, 23)
        LDU(c24, 24) LDU(c25, 25) LDU(c26, 26) LDU(c27, 27)
        LDU(c28, 28) LDU(c29, 29) LDU(c30, 30) LDU(c31, 31)
#undef LDU
    }
    sm[j] = 0.f;

    const float* pb = pre + b * DD + j;   // element stride per t = 512 floats
    float* mbp = mem + b * DD + j;

    // preload chunk 0 (t = 0..7)
    float p0 = pb[0 * 512], p1 = pb[1 * 512], p2 = pb[2 * 512], p3 = pb[3 * 512];
    float p4 = pb[4 * 512], p5 = pb[5 * 512], p6 = pb[6 * 512], p7 = pb[7 * 512];

    for (int c = 0; c < 128; ++c) {
        // prefetch next chunk's pre (last chunk reloads its own; unused)
        int nt0 = (c < 127) ? (c + 1) * 8 : 1016;
        const float* pn = pb + nt0 * 512;
        float q0 = pn[0 * 512], q1 = pn[1 * 512], q2 = pn[2 * 512], q3 = pn[3 * 512];
        float q4 = pn[4 * 512], q5 = pn[5 * 512], q6 = pn[6 * 512], q7 = pn[7 * 512];

        float m0, m1, m2, m3, m4r, m5, m6, m7;
#define STEP2(KK, UA, UB, UC, UD) {                             \
        f32x4 va = mv[2 * KK], vb = mv[2 * KK + 1];             \
        A0 += __builtin_shufflevector(va, va, 0, 1) * UA;       \
        A1 += __builtin_shufflevector(va, va, 2, 3) * UB;       \
        A2 += __builtin_shufflevector(vb, vb, 0, 1) * UC;       \
        A3 += __builtin_shufflevector(vb, vb, 2, 3) * UD; }
#define DOT_TANH(PIN, MOUT) {                                                  \
        const f32x4* mv = (const f32x4*)sm;                                    \
        f32x2 A0 = {0.f, 0.f}, A1 = {0.f, 0.f}, A2 = {0.f, 0.f}, A3 = {0.f, 0.f}; \
        STEP2(0, c0, c1, c2, c3)     STEP2(1, c4, c5, c6, c7)                  \
        STEP2(2, c8, c9, c10, c11)   STEP2(3, c12, c13, c14, c15)              \
        STEP2(4, c16, c17, c18, c19) STEP2(5, c20, c21, c22, c23)              \
        STEP2(6, c24, c25, c26, c27) STEP2(7, c28, c29, c30, c31)              \
        float s = ((A0.x + A0.y) + (A1.x + A1.y))                              \
                + ((A2.x + A2.y) + (A3.x + A3.y)) + PIN;                       \
        float ex = __expf(2.f * s);                                            \
        MOUT = 1.f - 2.f * __builtin_amdgcn_rcpf(ex + 1.f);                    \
        sm[j] = MOUT; }
        DOT_TANH(p0, m0) DOT_TANH(p1, m1) DOT_TANH(p2, m2) DOT_TANH(p3, m3)
        DOT_TANH(p4, m4r) DOT_TANH(p5, m5) DOT_TANH(p6, m6) DOT_TANH(p7, m7)
#undef DOT_TANH
#undef STEP2
        // batched stores (off the serial critical path)
        float* mp = mbp + c * 8 * 512;
        mp[0 * 512] = m0; mp[1 * 512] = m1; mp[2 * 512] = m2; mp[3 * 512] = m3;
        mp[4 * 512] = m4r; mp[5 * 512] = m5; mp[6 * 512] = m6; mp[7 * 512] = m7;
        p0 = q0; p1 = q1; p2 = q2; p3 = q3;
        p4 = q4; p5 = q5; p6 = q6; p7 = q7;
    }
}

// ---------------------------------------------------------------------------
// K3: expert FFN. block = (expert e, 64 tokens); wave w = 16 tokens.
//     GEMM1: h = gelu(emb @ W1_e + b1_e); LDS round-trip (C->A layout);
//     GEMM2: eo = h @ W2_e + b2_e -> bf16 eo[tok][e][d].
// ---------------------------------------------------------------------------
__global__ __launch_bounds__(256) void k_ffn(const u16* __restrict__ emb,
                                             const u16* __restrict__ W1T,
                                             const void* __restrict__ b1g,
                                             const u16* __restrict__ W2T,
                                             const void* __restrict__ b2g,
                                             const int* __restrict__ flag,
                                             u16* __restrict__ eo) {
    __shared__ u16 hh[4][16 * 264];          // 264 = 256 + 8 pad
    int isbf = *flag;
    int e = blockIdx.x, mb = blockIdx.y;
    int w = threadIdx.x >> 6, l = threadIdx.x & 63;
    int lr = l & 15, lq = l >> 4;
    int m0 = mb * 64 + w * 16;

    short8 a0 = ld8(emb + (m0 + lr) * DD + lq * 8);
    short8 a1 = ld8(emb + (m0 + lr) * DD + 32 + lq * 8);
    const u16* w1 = W1T + e * 16384;

    f32x4 acc[16];
#pragma unroll
    for (int nt = 0; nt < 16; nt++) {
        int n = nt * 16 + lr;
        short8 bf0 = ld8(w1 + n * DD + lq * 8);
        short8 bf1 = ld8(w1 + n * DD + 32 + lq * 8);
        f32x4 c = {0.f, 0.f, 0.f, 0.f};
        c = __builtin_amdgcn_mfma_f32_16x16x32_bf16(a0, bf0, c, 0, 0, 0);
        c = __builtin_amdgcn_mfma_f32_16x16x32_bf16(a1, bf1, c, 0, 0, 0);
        acc[nt] = c;
    }
    u16* hw = hh[w];
#pragma unroll
    for (int nt = 0; nt < 16; nt++) {
        int n = nt * 16 + lr;
        float bb = ldf(b1g, e * FF + n, isbf);
#pragma unroll
        for (int r = 0; r < 4; r++) {
            float xv = acc[nt][r] + bb;
            float g = 0.5f * xv * (1.f + erff(xv * 0.70710678118654752f));
            hw[(lq * 4 + r) * 264 + n] = f2bf(g);
        }
    }
    __syncthreads();

    f32x4 acc2[4];
#pragma unroll
    for (int dt = 0; dt < 4; dt++) acc2[dt] = (f32x4){0.f, 0.f, 0.f, 0.f};
    const u16* w2 = W2T + e * 16384;
#pragma unroll
    for (int kb = 0; kb < 8; kb++) {
        short8 af = ld8(hw + lr * 264 + kb * 32 + lq * 8);
#pragma unroll
        for (int dt = 0; dt < 4; dt++) {
            short8 bf = ld8(w2 + (dt * 16 + lr) * FF + kb * 32 + lq * 8);
            acc2[dt] = __builtin_amdgcn_mfma_f32_16x16x32_bf16(af, bf, acc2[dt], 0, 0, 0);
        }
    }
#pragma unroll
    for (int dt = 0; dt < 4; dt++) {
        int d = dt * 16 + lr;
        float bb = ldf(b2g, e * DD + d, isbf);
#pragma unroll
        for (int r = 0; r < 4; r++) {
            int tok = m0 + lq * 4 + r;
            eo[(tok * EE + e) * DD + d] = f2bf(acc2[dt][r] + bb);
        }
    }
}

// ---------------------------------------------------------------------------
// K4: gates[tok][:] = softmax(mem[t][b][:] @ Wg + bg).  thread = token.
// ---------------------------------------------------------------------------
__global__ __launch_bounds__(256) void k_gates(const float* __restrict__ mem,
                                               const void* __restrict__ Wg,
                                               const void* __restrict__ bg,
                                               const int* __restrict__ flag,
                                               float* __restrict__ gates) {
    __shared__ float sWg[DD * EE];
    int isbf = *flag;
    int tid = threadIdx.x;
    for (int i = tid; i < DD * EE; i += 256) sWg[i] = ldf(Wg, i, isbf);
    __syncthreads();

    int tok = blockIdx.x * 256 + tid;
    int b = tok >> 10, t = tok & 1023;
    const float* mr = mem + (t * BB + b) * DD;
    float z[EE];
#pragma unroll
    for (int e = 0; e < EE; e++) z[e] = ldf(bg, e, isbf);
    const float4* wg4 = (const float4*)sWg;
    const float4* mr4 = (const float4*)mr;
    for (int k4 = 0; k4 < 16; k4++) {
        float4 mv = mr4[k4];
        float m[4] = {mv.x, mv.y, mv.z, mv.w};
#pragma unroll
        for (int kk = 0; kk < 4; kk++) {
            int k = k4 * 4 + kk;
            float4 wa = wg4[k * 2], wb = wg4[k * 2 + 1];
            z[0] += m[kk] * wa.x; z[1] += m[kk] * wa.y;
            z[2] += m[kk] * wa.z; z[3] += m[kk] * wa.w;
            z[4] += m[kk] * wb.x; z[5] += m[kk] * wb.y;
            z[6] += m[kk] * wb.z; z[7] += m[kk] * wb.w;
        }
    }
    float zm = z[0];
#pragma unroll
    for (int e = 1; e < EE; e++) zm = fmaxf(zm, z[e]);
    float sum = 0.f;
#pragma unroll
    for (int e = 0; e < EE; e++) { z[e] = __expf(z[e] - zm); sum += z[e]; }
    float rs = __builtin_amdgcn_rcpf(sum);
#pragma unroll
    for (int e = 0; e < EE; e++) gates[tok * EE + e] = z[e] * rs;
}

// ---------------------------------------------------------------------------
// K5: out = LayerNorm(emb + sum_e gates_e * eo_e) -> canonical bf16 outb.
// ---------------------------------------------------------------------------
__global__ __launch_bounds__(256) void k_ln(const u16* __restrict__ emb,
                                            const u16* __restrict__ eo,
                                            const float* __restrict__ gates,
                                            const void* __restrict__ ln_g,
                                            const void* __restrict__ ln_b,
                                            const int* __restrict__ flag,
                                            u16* __restrict__ outb) {
    int isbf = *flag;
    int w = threadIdx.x >> 6, l = threadIdx.x & 63;
    int tok = blockIdx.x * 4 + w;
    const float* g = gates + tok * EE;
    const u16* er = eo + tok * EE * DD;
    float moe = 0.f;
#pragma unroll
    for (int e = 0; e < EE; e++) moe += g[e] * bf2f(er[e * DD + l]);
    float y = bf2f(emb[tok * DD + l]) + moe;
    float s = y;
#pragma unroll
    for (int off = 32; off > 0; off >>= 1) s += __shfl_xor(s, off, 64);
    float mu = s * (1.f / 64.f);
    float d = y - mu;
    float s2 = d * d;
#pragma unroll
    for (int off = 32; off > 0; off >>= 1) s2 += __shfl_xor(s2, off, 64);
    float var = s2 * (1.f / 64.f);
    float r = rsqrtf(var + 1e-5f);
    float o = ldf(ln_g, l, isbf) * d * r + ldf(ln_b, l, isbf);
    outb[tok * DD + l] = f2bf(o);
}

// ---------------------------------------------------------------------------
// K6: head GEMM. logits = out @ head_W + head_b  [8192 x 16000].
//     Output dtype per flag (bf16 or f32).
// ---------------------------------------------------------------------------
__global__ __launch_bounds__(256) void k_head(const u16* __restrict__ outb,
                                              const u16* __restrict__ headWT,
                                              const void* __restrict__ head_b,
                                              const int* __restrict__ flag,
                                              void* __restrict__ logits) {
    int isbf = *flag;
    int nb = blockIdx.x, mb = blockIdx.y;
    int w = threadIdx.x >> 6, l = threadIdx.x & 63;
    int lr = l & 15, lq = l >> 4;
    int m0 = mb * 64 + w * 16;
    int n0 = nb * 256;
    int ntc = (nb == 62) ? 8 : 16;

    short8 a0 = ld8(outb + (m0 + lr) * DD + lq * 8);
    short8 a1 = ld8(outb + (m0 + lr) * DD + 32 + lq * 8);

    for (int nt = 0; nt < ntc; nt++) {
        int n = n0 + nt * 16 + lr;
        short8 bf0 = ld8(headWT + n * DD + lq * 8);
        short8 bf1 = ld8(headWT + n * DD + 32 + lq * 8);
        f32x4 c = {0.f, 0.f, 0.f, 0.f};
        c = __builtin_amdgcn_mfma_f32_16x16x32_bf16(a0, bf0, c, 0, 0, 0);
        c = __builtin_amdgcn_mfma_f32_16x16x32_bf16(a1, bf1, c, 0, 0, 0);
        float hb = ldf(head_b, n, isbf);
        if (isbf) {
#pragma unroll
            for (int r = 0; r < 4; r++)
                ((u16*)logits)[(m0 + lq * 4 + r) * VV + n] = f2bf(c[r] + hb);
        } else {
#pragma unroll
            for (int r = 0; r < 4; r++)
                ((float*)logits)[(m0 + lq * 4 + r) * VV + n] = c[r] + hb;
        }
    }
}

// ---------------------------------------------------------------------------
extern "C" void kernel_launch(void* const* d_in, const int* in_sizes, int n_in,
                              void* d_out, int out_size, void* d_ws, size_t ws_size,
                              hipStream_t stream) {
    const int*  x      = (const int*)d_in[0];
    const void* tbl    = d_in[1];
    const void* Wm     = d_in[2];
    const void* Um     = d_in[3];
    const void* bm     = d_in[4];
    const void* Wg     = d_in[5];
    const void* bg     = d_in[6];
    const void* W1     = d_in[7];
    const void* b1     = d_in[8];
    const void* W2     = d_in[9];
    const void* b2     = d_in[10];
    const void* ln_g   = d_in[11];
    const void* ln_b   = d_in[12];
    const void* headW  = d_in[13];
    const void* head_b = d_in[14];

    char* w = (char*)d_ws;
    int*   flag   = (int*)(w);                    // 256 B
    u16*   headWT = (u16*)(w + 0x0000100);        // 2,048,000 B
    u16*   W1T    = (u16*)(w + 0x0200000);        //   262,144 B
    u16*   W2T    = (u16*)(w + 0x0240000);        //   262,144 B
    u16*   emb    = (u16*)(w + 0x0280000);        // 1,048,576 B
    u16*   outb   = (u16*)(w + 0x0380000);        // 1,048,576 B
    float* pre    = (float*)(w + 0x0480000);      // 2,097,152 B
    float* mem    = (float*)(w + 0x0680000);      // 2,097,152 B
    float* gates  = (float*)(w + 0x0880000);      //   262,144 B
    u16*   eo     = (u16*)(w + 0x08C0000);        // 8,388,608 B  (end 17.6 MB)

    k_sniff<<<dim3(1), dim3(256), 0, stream>>>((const u32*)tbl, flag);
    k_transph<<<dim3(VV / 64), dim3(256), 0, stream>>>(headW, flag, headWT);
    k_transpose<<<dim3(2 * EE * DD * FF / 256), dim3(256), 0, stream>>>(
        W1, W2, flag, W1T, W2T);
    k_embed_pre<<<dim3(BT * 4 / 256), dim3(256), 0, stream>>>(x, tbl, Wm, bm, flag, emb, pre);
    k_scan<<<dim3(BB), dim3(64), 0, stream>>>(pre, Um, flag, mem);
    k_ffn<<<dim3(EE, BT / 64), dim3(256), 0, stream>>>(emb, W1T, b1, W2T, b2, flag, eo);
    k_gates<<<dim3(BT / 256), dim3(256), 0, stream>>>(mem, Wg, bg, flag, gates);
    k_ln<<<dim3(BT / 4), dim3(256), 0, stream>>>(emb, eo, gates, ln_g, ln_b, flag, outb);
    k_head<<<dim3(63, BT / 64), dim3(256), 0, stream>>>(outb, headWT, head_b, flag, d_out);
}

// Round 4
// 974.963 us; speedup vs baseline: 1.1372x; 1.1372x over previous
//
#include <hip/hip_runtime.h>

// ---------------------------------------------------------------------------
// MoE LM forward, MI355X round 6.
// Dual-dtype (runtime-sniffed bf16 vs f32 inputs/outputs), f32 accumulation.
// Pipeline: k_sniff -> {k_transph, k_transpose} -> k_embed_pre
//           -> k_scan_ffn (fused: scan blocks 0-7 + ffn blocks 8-1031)
//           -> k_gates -> k_ln -> k_head.
// R6: (a) k_scan Um column forced VGPR-resident via asm "+v" barrier after
//     the load -- R3/R4/R5 all showed VGPR_Count 44-52: the compiler
//     REMATERIALIZES provably-reloadable loop-invariant loads instead of
//     keeping 64 regs live; the asm makes the values opaque (non-remat).
//     (b) revert to R4 1-step loop (R5 chunking regressed 283->363 us).
//     (c) scan (8 CUs busy, 248 idle for ~300 us) fused with the
//     independent ffn into one dispatch to overlap.
// ---------------------------------------------------------------------------

#define VV 16000
#define BB 8
#define TT 1024
#define DD 64
#define FF 256
#define EE 8
#define BT 8192   // B*T

typedef unsigned short u16;
typedef unsigned int   u32;
typedef __attribute__((ext_vector_type(8))) short short8;   // 8 x bf16 (4 VGPR)
typedef __attribute__((ext_vector_type(4))) float f32x4;    // MFMA C/D
typedef __attribute__((ext_vector_type(2))) float f32x2;    // v_pk_fma_f32

__device__ __forceinline__ float bf2f(u16 u) {
    union { u32 i; float f; } v; v.i = ((u32)u) << 16; return v.f;
}
__device__ __forceinline__ u16 f2bf(float f) {  // round-to-nearest-even
    union { float f; u32 i; } v; v.f = f;
    u32 lsb = (v.i >> 16) & 1u;
    return (u16)((v.i + 0x7fffu + lsb) >> 16);
}
__device__ __forceinline__ short8 ld8(const u16* p) { return *(const short8*)p; }
// dual-dtype scalar load: input array is bf16 (isbf=1) or f32 (isbf=0)
__device__ __forceinline__ float ldf(const void* p, int i, int isbf) {
    return isbf ? bf2f(((const u16*)p)[i]) : ((const float*)p)[i];
}

// ---------------------------------------------------------------------------
// K-1: dtype sniffer. 256 samples, majority vote on bf16-plausible exponent.
// ---------------------------------------------------------------------------
__global__ __launch_bounds__(256) void k_sniff(const u32* __restrict__ tblw,
                                               int* __restrict__ flag) {
    __shared__ int c;
    int tid = threadIdx.x;
    if (tid == 0) c = 0;
    __syncthreads();
    u32 u = tblw[tid];
    u32 lo = u & 0xFFFFu;
    u32 e = (lo >> 7) & 0xFFu;
    int hit = ((e >= 0x60u && e <= 0x7Eu) || lo == 0u) ? 1 : 0;
    atomicAdd(&c, hit);
    __syncthreads();
    if (tid == 0) *flag = (c >= 192) ? 1 : 0;
}

// ---------------------------------------------------------------------------
// K0a: headW [64][16000] -> headWT [16000][64] bf16, LDS-tiled 64x64.
// ---------------------------------------------------------------------------
__global__ __launch_bounds__(256) void k_transph(const void* __restrict__ headW,
                                                 const int* __restrict__ flag,
                                                 u16* __restrict__ headWT) {
    __shared__ float tile[DD][DD + 1];
    int isbf = *flag;
    int v0 = blockIdx.x * 64;
    int tid = threadIdx.x;
    int c = tid & 63, rq = tid >> 6;      // c: lane col, rq: row quarter
#pragma unroll
    for (int i = 0; i < 16; i++) {
        int k = i * 4 + rq;
        tile[k][c] = ldf(headW, k * VV + v0 + c, isbf);
    }
    __syncthreads();
#pragma unroll
    for (int i = 0; i < 16; i++) {
        int v = i * 4 + rq;
        headWT[(v0 + v) * DD + c] = f2bf(tile[c][v]);
    }
}

// ---------------------------------------------------------------------------
// K0b: W1/W2 -> canonical bf16 B^T layout (small: 262K elements).
//   W1T[e][f][d] = W1[e][d][f];  W2T[e][d][f] = W2[e][f][d]
// ---------------------------------------------------------------------------
__global__ __launch_bounds__(256) void k_transpose(const void* __restrict__ W1,
                                                   const void* __restrict__ W2,
                                                   const int* __restrict__ flag,
                                                   u16* __restrict__ W1T,
                                                   u16* __restrict__ W2T) {
    int isbf = *flag;
    int idx = blockIdx.x * 256 + threadIdx.x;   // grid 1024 -> 262144
    if (idx < EE * DD * FF) {
        int e = idx >> 14, r = idx & 16383, d = r >> 8, f = r & 255;
        W1T[e * 16384 + f * DD + d] = f2bf(ldf(W1, idx, isbf));
    } else {
        int j2 = idx - EE * DD * FF;
        int e = j2 >> 14, r = j2 & 16383, f = r >> 6, d = r & 63;
        W2T[e * 16384 + d * FF + f] = f2bf(ldf(W2, j2, isbf));
    }
}

// ---------------------------------------------------------------------------
// K1: gather embeddings (-> canonical bf16 emb) + pre[t][b][:] = emb@Wm + bm.
//     4 threads per token (q = quarter of the 64 output columns).
// ---------------------------------------------------------------------------
__global__ __launch_bounds__(256) void k_embed_pre(const int* __restrict__ x,
                                                   const void* __restrict__ tbl,
                                                   const void* __restrict__ Wm,
                                                   const void* __restrict__ bm,
                                                   const int* __restrict__ flag,
                                                   u16* __restrict__ emb,
                                                   float* __restrict__ pre) {
    __shared__ float sWm[DD * DD];
    __shared__ float sbm[DD];
    int isbf = *flag;
    int tid = threadIdx.x;
    for (int i = tid; i < DD * DD; i += 256) sWm[i] = ldf(Wm, i, isbf);
    if (tid < DD) sbm[tid] = ldf(bm, tid, isbf);
    __syncthreads();

    int gi = blockIdx.x * 256 + tid;           // grid = 128
    int tok = gi >> 2, q = gi & 3;             // 4 threads per token
    int id = x[tok];
    float e[DD];
    if (isbf) {
        const uint4* src = (const uint4*)((const u16*)tbl + id * DD);
        uint4* dst = (uint4*)(emb + tok * DD);
#pragma unroll
        for (int i = 0; i < 8; i++) {
            uint4 v = src[i];
            if ((i >> 1) == q) dst[i] = v;     // each q writes 2 of 8 uint4
            const u16* pu = (const u16*)&v;
#pragma unroll
            for (int j = 0; j < 8; j++) e[i * 8 + j] = bf2f(pu[j]);
        }
    } else {
        const float4* src = (const float4*)((const float*)tbl + id * DD);
        u16* dst = emb + tok * DD;
#pragma unroll
        for (int i = 0; i < 16; i++) {
            float4 v = src[i];
            e[i * 4 + 0] = v.x; e[i * 4 + 1] = v.y;
            e[i * 4 + 2] = v.z; e[i * 4 + 3] = v.w;
            if ((i >> 2) == q) {               // each q writes 4 of 16 pairs
                u32 p0 = (u32)f2bf(v.x) | ((u32)f2bf(v.y) << 16);
                u32 p1 = (u32)f2bf(v.z) | ((u32)f2bf(v.w) << 16);
                ((u32*)dst)[i * 2] = p0;
                ((u32*)dst)[i * 2 + 1] = p1;
            }
        }
    }
    int b = tok >> 10, t = tok & 1023;
    float* prow = pre + (t * BB + b) * DD + q * 16;
#pragma unroll
    for (int j4 = 0; j4 < 4; j4++) {
        int j0 = q * 16 + j4 * 4;
        float a0 = sbm[j0 + 0], a1 = sbm[j0 + 1];
        float a2 = sbm[j0 + 2], a3 = sbm[j0 + 3];
#pragma unroll
        for (int k = 0; k < DD; k++) {
            float ek = e[k];
            float4 wv = *(const float4*)&sWm[k * DD + j0];
            a0 += ek * wv.x; a1 += ek * wv.y;
            a2 += ek * wv.z; a3 += ek * wv.w;
        }
        ((float4*)prow)[j4] = make_float4(a0, a1, a2, a3);
    }
}

// ---------------------------------------------------------------------------
// K2: FUSED scan + expert FFN (independent inputs -> run concurrently).
//   blocks 0..7   : serial scan, wave 0 only (1 block per batch row).
//     lane j owns column j; Um column in 32 f32x2 forced VGPR-resident via
//     an asm "+v" barrier (blocks rematerialization-from-L2 -- R3/R4/R5
//     all re-loaded Um every step, VGPR_Count 44-52 proved it).
//     mem_t = tanh(pre_t + mem_{t-1} @ Um), stored f32 [t][b][d].
//   blocks 8..1031: expert FFN, (expert e, 64 tokens) per block, 4 waves.
//     GEMM1: h = gelu(emb @ W1_e + b1_e); LDS round-trip;
//     GEMM2: eo = h @ W2_e + b2_e -> bf16 eo[tok][e][d].
// ---------------------------------------------------------------------------
__global__ __launch_bounds__(256, 1) void k_scan_ffn(
        const float* __restrict__ pre, const void* __restrict__ Um,
        const u16* __restrict__ emb, const u16* __restrict__ W1T,
        const void* __restrict__ b1g, const u16* __restrict__ W2T,
        const void* __restrict__ b2g, const int* __restrict__ flag,
        float* __restrict__ mem, u16* __restrict__ eo) {
    __shared__ u16 hh[4][16 * 264];          // 33 KB; scan uses first 256 B
    int isbf = *flag;
    int bid = blockIdx.x;

    if (bid < BB) {
        // ---------------- scan path: single wave ----------------
        if (threadIdx.x >= 64) return;
        int b = bid, j = threadIdx.x;
        float* sm = (float*)hh;

        f32x2 c0, c1, c2, c3, c4, c5, c6, c7, c8, c9, c10, c11, c12, c13,
              c14, c15, c16, c17, c18, c19, c20, c21, c22, c23, c24, c25,
              c26, c27, c28, c29, c30, c31;
        if (isbf) {
            const u16* up = (const u16*)Um + j;
#define LDU(VAR, I) VAR = (f32x2){bf2f(up[(2 * I) * DD]), bf2f(up[(2 * I + 1) * DD])};
            LDU(c0, 0)  LDU(c1, 1)  LDU(c2, 2)  LDU(c3, 3)
            LDU(c4, 4)  LDU(c5, 5)  LDU(c6, 6)  LDU(c7, 7)
            LDU(c8, 8)  LDU(c9, 9)  LDU(c10, 10) LDU(c11, 11)
            LDU(c12, 12) LDU(c13, 13) LDU(c14, 14) LDU(c15, 15)
            LDU(c16, 16) LDU(c17, 17) LDU(c18, 18) LDU(c19, 19)
            LDU(c20, 20) LDU(c21, 21) LDU(c22, 22) LDU(c23, 23)
            LDU(c24, 24) LDU(c25, 25) LDU(c26, 26) LDU(c27, 27)
            LDU(c28, 28) LDU(c29, 29) LDU(c30, 30) LDU(c31, 31)
#undef LDU
        } else {
            const float* up = (const float*)Um + j;
#define LDU(VAR, I) VAR = (f32x2){up[(2 * I) * DD], up[(2 * I + 1) * DD]};
            LDU(c0, 0)  LDU(c1, 1)  LDU(c2, 2)  LDU(c3, 3)
            LDU(c4, 4)  LDU(c5, 5)  LDU(c6, 6)  LDU(c7, 7)
            LDU(c8, 8)  LDU(c9, 9)  LDU(c10, 10) LDU(c11, 11)
            LDU(c12, 12) LDU(c13, 13) LDU(c14, 14) LDU(c15, 15)
            LDU(c16, 16) LDU(c17, 17) LDU(c18, 18) LDU(c19, 19)
            LDU(c20, 20) LDU(c21, 21) LDU(c22, 22) LDU(c23, 23)
            LDU(c24, 24) LDU(c25, 25) LDU(c26, 26) LDU(c27, 27)
            LDU(c28, 28) LDU(c29, 29) LDU(c30, 30) LDU(c31, 31)
#undef LDU
        }
        // Force residency: opaque redefinition kills remat-from-memory.
        asm volatile("" : "+v"(c0), "+v"(c1), "+v"(c2), "+v"(c3),
                          "+v"(c4), "+v"(c5), "+v"(c6), "+v"(c7));
        asm volatile("" : "+v"(c8), "+v"(c9), "+v"(c10), "+v"(c11),
                          "+v"(c12), "+v"(c13), "+v"(c14), "+v"(c15));
        asm volatile("" : "+v"(c16), "+v"(c17), "+v"(c18), "+v"(c19),
                          "+v"(c20), "+v"(c21), "+v"(c22), "+v"(c23));
        asm volatile("" : "+v"(c24), "+v"(c25), "+v"(c26), "+v"(c27),
                          "+v"(c28), "+v"(c29), "+v"(c30), "+v"(c31));
        sm[j] = 0.f;

        float pcur = pre[b * DD + j];   // t = 0
        for (int t = 0; t < TT; t++) {
            int tn = (t + 1 < TT) ? t + 1 : t;
            float pnext = pre[(tn * BB + b) * DD + j];   // prefetch
            const f32x4* mv = (const f32x4*)sm;
            f32x2 A0 = {0.f, 0.f}, A1 = {0.f, 0.f};
            f32x2 A2 = {0.f, 0.f}, A3 = {0.f, 0.f};
#define STEP2(KK, UA, UB, UC, UD) {                             \
            f32x4 va = mv[2 * KK], vb = mv[2 * KK + 1];         \
            A0 += __builtin_shufflevector(va, va, 0, 1) * UA;   \
            A1 += __builtin_shufflevector(va, va, 2, 3) * UB;   \
            A2 += __builtin_shufflevector(vb, vb, 0, 1) * UC;   \
            A3 += __builtin_shufflevector(vb, vb, 2, 3) * UD; }
            STEP2(0, c0, c1, c2, c3)     STEP2(1, c4, c5, c6, c7)
            STEP2(2, c8, c9, c10, c11)   STEP2(3, c12, c13, c14, c15)
            STEP2(4, c16, c17, c18, c19) STEP2(5, c20, c21, c22, c23)
            STEP2(6, c24, c25, c26, c27) STEP2(7, c28, c29, c30, c31)
#undef STEP2
            float s = ((A0.x + A0.y) + (A1.x + A1.y))
                    + ((A2.x + A2.y) + (A3.x + A3.y)) + pcur;
            // tanh(s) = 1 - 2/(e^{2s}+1); exp->inf / ->0 both give +/-1
            float ex = __expf(2.f * s);
            float mn = 1.f - 2.f * __builtin_amdgcn_rcpf(ex + 1.f);
            sm[j] = mn;     // single wave: DS in-order; next iter sees it
            mem[(t * BB + b) * DD + j] = mn;
            pcur = pnext;
        }
        return;
    }

    // ---------------- ffn path: 4 waves ----------------
    int fid = bid - BB;
    int e = fid >> 7, mb = fid & 127;
    int w = threadIdx.x >> 6, l = threadIdx.x & 63;
    int lr = l & 15, lq = l >> 4;
    int m0 = mb * 64 + w * 16;

    short8 a0 = ld8(emb + (m0 + lr) * DD + lq * 8);
    short8 a1 = ld8(emb + (m0 + lr) * DD + 32 + lq * 8);
    const u16* w1 = W1T + e * 16384;

    f32x4 acc[16];
#pragma unroll
    for (int nt = 0; nt < 16; nt++) {
        int n = nt * 16 + lr;
        short8 bf0 = ld8(w1 + n * DD + lq * 8);
        short8 bf1 = ld8(w1 + n * DD + 32 + lq * 8);
        f32x4 c = {0.f, 0.f, 0.f, 0.f};
        c = __builtin_amdgcn_mfma_f32_16x16x32_bf16(a0, bf0, c, 0, 0, 0);
        c = __builtin_amdgcn_mfma_f32_16x16x32_bf16(a1, bf1, c, 0, 0, 0);
        acc[nt] = c;
    }
    u16* hw = hh[w];
#pragma unroll
    for (int nt = 0; nt < 16; nt++) {
        int n = nt * 16 + lr;
        float bb = ldf(b1g, e * FF + n, isbf);
#pragma unroll
        for (int r = 0; r < 4; r++) {
            float xv = acc[nt][r] + bb;
            float g = 0.5f * xv * (1.f + erff(xv * 0.70710678118654752f));
            hw[(lq * 4 + r) * 264 + n] = f2bf(g);
        }
    }
    __syncthreads();

    f32x4 acc2[4];
#pragma unroll
    for (int dt = 0; dt < 4; dt++) acc2[dt] = (f32x4){0.f, 0.f, 0.f, 0.f};
    const u16* w2 = W2T + e * 16384;
#pragma unroll
    for (int kb = 0; kb < 8; kb++) {
        short8 af = ld8(hw + lr * 264 + kb * 32 + lq * 8);
#pragma unroll
        for (int dt = 0; dt < 4; dt++) {
            short8 bf = ld8(w2 + (dt * 16 + lr) * FF + kb * 32 + lq * 8);
            acc2[dt] = __builtin_amdgcn_mfma_f32_16x16x32_bf16(af, bf, acc2[dt], 0, 0, 0);
        }
    }
#pragma unroll
    for (int dt = 0; dt < 4; dt++) {
        int d = dt * 16 + lr;
        float bb = ldf(b2g, e * DD + d, isbf);
#pragma unroll
        for (int r = 0; r < 4; r++) {
            int tok = m0 + lq * 4 + r;
            eo[(tok * EE + e) * DD + d] = f2bf(acc2[dt][r] + bb);
        }
    }
}

// ---------------------------------------------------------------------------
// K4: gates[tok][:] = softmax(mem[t][b][:] @ Wg + bg).  thread = token.
// ---------------------------------------------------------------------------
__global__ __launch_bounds__(256) void k_gates(const float* __restrict__ mem,
                                               const void* __restrict__ Wg,
                                               const void* __restrict__ bg,
                                               const int* __restrict__ flag,
                                               float* __restrict__ gates) {
    __shared__ float sWg[DD * EE];
    int isbf = *flag;
    int tid = threadIdx.x;
    for (int i = tid; i < DD * EE; i += 256) sWg[i] = ldf(Wg, i, isbf);
    __syncthreads();

    int tok = blockIdx.x * 256 + tid;
    int b = tok >> 10, t = tok & 1023;
    const float* mr = mem + (t * BB + b) * DD;
    float z[EE];
#pragma unroll
    for (int e = 0; e < EE; e++) z[e] = ldf(bg, e, isbf);
    const float4* wg4 = (const float4*)sWg;
    const float4* mr4 = (const float4*)mr;
    for (int k4 = 0; k4 < 16; k4++) {
        float4 mv = mr4[k4];
        float m[4] = {mv.x, mv.y, mv.z, mv.w};
#pragma unroll
        for (int kk = 0; kk < 4; kk++) {
            int k = k4 * 4 + kk;
            float4 wa = wg4[k * 2], wb = wg4[k * 2 + 1];
            z[0] += m[kk] * wa.x; z[1] += m[kk] * wa.y;
            z[2] += m[kk] * wa.z; z[3] += m[kk] * wa.w;
            z[4] += m[kk] * wb.x; z[5] += m[kk] * wb.y;
            z[6] += m[kk] * wb.z; z[7] += m[kk] * wb.w;
        }
    }
    float zm = z[0];
#pragma unroll
    for (int e = 1; e < EE; e++) zm = fmaxf(zm, z[e]);
    float sum = 0.f;
#pragma unroll
    for (int e = 0; e < EE; e++) { z[e] = __expf(z[e] - zm); sum += z[e]; }
    float rs = __builtin_amdgcn_rcpf(sum);
#pragma unroll
    for (int e = 0; e < EE; e++) gates[tok * EE + e] = z[e] * rs;
}

// ---------------------------------------------------------------------------
// K5: out = LayerNorm(emb + sum_e gates_e * eo_e) -> canonical bf16 outb.
// ---------------------------------------------------------------------------
__global__ __launch_bounds__(256) void k_ln(const u16* __restrict__ emb,
                                            const u16* __restrict__ eo,
                                            const float* __restrict__ gates,
                                            const void* __restrict__ ln_g,
                                            const void* __restrict__ ln_b,
                                            const int* __restrict__ flag,
                                            u16* __restrict__ outb) {
    int isbf = *flag;
    int w = threadIdx.x >> 6, l = threadIdx.x & 63;
    int tok = blockIdx.x * 4 + w;
    const float* g = gates + tok * EE;
    const u16* er = eo + tok * EE * DD;
    float moe = 0.f;
#pragma unroll
    for (int e = 0; e < EE; e++) moe += g[e] * bf2f(er[e * DD + l]);
    float y = bf2f(emb[tok * DD + l]) + moe;
    float s = y;
#pragma unroll
    for (int off = 32; off > 0; off >>= 1) s += __shfl_xor(s, off, 64);
    float mu = s * (1.f / 64.f);
    float d = y - mu;
    float s2 = d * d;
#pragma unroll
    for (int off = 32; off > 0; off >>= 1) s2 += __shfl_xor(s2, off, 64);
    float var = s2 * (1.f / 64.f);
    float r = rsqrtf(var + 1e-5f);
    float o = ldf(ln_g, l, isbf) * d * r + ldf(ln_b, l, isbf);
    outb[tok * DD + l] = f2bf(o);
}

// ---------------------------------------------------------------------------
// K6: head GEMM. logits = out @ head_W + head_b  [8192 x 16000].
//     Output dtype per flag (bf16 or f32).
// ---------------------------------------------------------------------------
__global__ __launch_bounds__(256) void k_head(const u16* __restrict__ outb,
                                              const u16* __restrict__ headWT,
                                              const void* __restrict__ head_b,
                                              const int* __restrict__ flag,
                                              void* __restrict__ logits) {
    int isbf = *flag;
    int nb = blockIdx.x, mb = blockIdx.y;
    int w = threadIdx.x >> 6, l = threadIdx.x & 63;
    int lr = l & 15, lq = l >> 4;
    int m0 = mb * 64 + w * 16;
    int n0 = nb * 256;
    int ntc = (nb == 62) ? 8 : 16;

    short8 a0 = ld8(outb + (m0 + lr) * DD + lq * 8);
    short8 a1 = ld8(outb + (m0 + lr) * DD + 32 + lq * 8);

    for (int nt = 0; nt < ntc; nt++) {
        int n = n0 + nt * 16 + lr;
        short8 bf0 = ld8(headWT + n * DD + lq * 8);
        short8 bf1 = ld8(headWT + n * DD + 32 + lq * 8);
        f32x4 c = {0.f, 0.f, 0.f, 0.f};
        c = __builtin_amdgcn_mfma_f32_16x16x32_bf16(a0, bf0, c, 0, 0, 0);
        c = __builtin_amdgcn_mfma_f32_16x16x32_bf16(a1, bf1, c, 0, 0, 0);
        float hb = ldf(head_b, n, isbf);
        if (isbf) {
#pragma unroll
            for (int r = 0; r < 4; r++)
                ((u16*)logits)[(m0 + lq * 4 + r) * VV + n] = f2bf(c[r] + hb);
        } else {
#pragma unroll
            for (int r = 0; r < 4; r++)
                ((float*)logits)[(m0 + lq * 4 + r) * VV + n] = c[r] + hb;
        }
    }
}

// ---------------------------------------------------------------------------
extern "C" void kernel_launch(void* const* d_in, const int* in_sizes, int n_in,
                              void* d_out, int out_size, void* d_ws, size_t ws_size,
                              hipStream_t stream) {
    const int*  x      = (const int*)d_in[0];
    const void* tbl    = d_in[1];
    const void* Wm     = d_in[2];
    const void* Um     = d_in[3];
    const void* bm     = d_in[4];
    const void* Wg     = d_in[5];
    const void* bg     = d_in[6];
    const void* W1     = d_in[7];
    const void* b1     = d_in[8];
    const void* W2     = d_in[9];
    const void* b2     = d_in[10];
    const void* ln_g   = d_in[11];
    const void* ln_b   = d_in[12];
    const void* headW  = d_in[13];
    const void* head_b = d_in[14];

    char* w = (char*)d_ws;
    int*   flag   = (int*)(w);                    // 256 B
    u16*   headWT = (u16*)(w + 0x0000100);        // 2,048,000 B
    u16*   W1T    = (u16*)(w + 0x0200000);        //   262,144 B
    u16*   W2T    = (u16*)(w + 0x0240000);        //   262,144 B
    u16*   emb    = (u16*)(w + 0x0280000);        // 1,048,576 B
    u16*   outb   = (u16*)(w + 0x0380000);        // 1,048,576 B
    float* pre    = (float*)(w + 0x0480000);      // 2,097,152 B
    float* mem    = (float*)(w + 0x0680000);      // 2,097,152 B
    float* gates  = (float*)(w + 0x0880000);      //   262,144 B
    u16*   eo     = (u16*)(w + 0x08C0000);        // 8,388,608 B  (end 17.6 MB)

    k_sniff<<<dim3(1), dim3(256), 0, stream>>>((const u32*)tbl, flag);
    k_transph<<<dim3(VV / 64), dim3(256), 0, stream>>>(headW, flag, headWT);
    k_transpose<<<dim3(2 * EE * DD * FF / 256), dim3(256), 0, stream>>>(
        W1, W2, flag, W1T, W2T);
    k_embed_pre<<<dim3(BT * 4 / 256), dim3(256), 0, stream>>>(x, tbl, Wm, bm, flag, emb, pre);
    k_scan_ffn<<<dim3(BB + EE * (BT / 64)), dim3(256), 0, stream>>>(
        pre, Um, emb, W1T, b1, W2T, b2, flag, mem, eo);
    k_gates<<<dim3(BT / 256), dim3(256), 0, stream>>>(mem, Wg, bg, flag, gates);
    k_ln<<<dim3(BT / 4), dim3(256), 0, stream>>>(emb, eo, gates, ln_g, ln_b, flag, outb);
    k_head<<<dim3(63, BT / 64), dim3(256), 0, stream>>>(outb, headWT, head_b, flag, d_out);
}

// Round 5
// 949.709 us; speedup vs baseline: 1.1674x; 1.0266x over previous
//
#include <hip/hip_runtime.h>

// ---------------------------------------------------------------------------
// MoE LM forward, MI355X round 7.
// Dual-dtype (runtime-sniffed bf16 vs f32 inputs/outputs), f32 accumulation.
// R7: time-chunked software pipeline. The scan emits mem[] monotonically in
//     t, so gates/ln/head for chunk c depend only on scan chunk c. Stream
//     ordering is the synchronization:
//       sniff -> k_pre(embed+transph+transpose)
//       M2: scan c0 | ffn c0
//       M3: scan c1 | ffn c1 | gates c0
//       M4: scan c2 | ffn c2 | gates c1 | ln c0
//       M5: scan c3 | ffn c3 | gates c2 | ln c1 | head c0
//       M6:                    gates c3 | ln c2 | head c1
//       M7:                               ln c3 | head c2
//       M8:                                       head c3
//     Scan chunk (~75us) is the long pole per launch; everything else hides
//     under it.  All role bodies are verbatim R6 code (numerics identical),
//     only block-index remapping.  Scan keeps the R6 asm "+v" residency
//     trick for the Um column.
// ---------------------------------------------------------------------------

#define VV 16000
#define BB 8
#define TT 1024
#define DD 64
#define FF 256
#define EE 8
#define BT 8192   // B*T
#define CT 256    // timesteps per pipeline chunk (4 chunks)

typedef unsigned short u16;
typedef unsigned int   u32;
typedef __attribute__((ext_vector_type(8))) short short8;   // 8 x bf16 (4 VGPR)
typedef __attribute__((ext_vector_type(4))) float f32x4;    // MFMA C/D
typedef __attribute__((ext_vector_type(2))) float f32x2;    // v_pk_fma_f32

__device__ __forceinline__ float bf2f(u16 u) {
    union { u32 i; float f; } v; v.i = ((u32)u) << 16; return v.f;
}
__device__ __forceinline__ u16 f2bf(float f) {  // round-to-nearest-even
    union { float f; u32 i; } v; v.f = f;
    u32 lsb = (v.i >> 16) & 1u;
    return (u16)((v.i + 0x7fffu + lsb) >> 16);
}
__device__ __forceinline__ short8 ld8(const u16* p) { return *(const short8*)p; }
// dual-dtype scalar load: input array is bf16 (isbf=1) or f32 (isbf=0)
__device__ __forceinline__ float ldf(const void* p, int i, int isbf) {
    return isbf ? bf2f(((const u16*)p)[i]) : ((const float*)p)[i];
}

// ---------------------------------------------------------------------------
// K-1: dtype sniffer. 256 samples, majority vote on bf16-plausible exponent.
// ---------------------------------------------------------------------------
__global__ __launch_bounds__(256) void k_sniff(const u32* __restrict__ tblw,
                                               int* __restrict__ flag) {
    __shared__ int c;
    int tid = threadIdx.x;
    if (tid == 0) c = 0;
    __syncthreads();
    u32 u = tblw[tid];
    u32 lo = u & 0xFFFFu;
    u32 e = (lo >> 7) & 0xFFu;
    int hit = ((e >= 0x60u && e <= 0x7Eu) || lo == 0u) ? 1 : 0;
    atomicAdd(&c, hit);
    __syncthreads();
    if (tid == 0) *flag = (c >= 192) ? 1 : 0;
}

// ---------------------------------------------------------------------------
// K0: fused prologue.
//   blocks [0,128)    : embed gather + pre = emb@Wm + bm (4 threads/token)
//   blocks [128,378)  : headW -> headWT bf16, LDS-tiled 64x64 transpose
//   blocks [378,1402) : W1/W2 -> canonical bf16 B^T layout
// ---------------------------------------------------------------------------
__global__ __launch_bounds__(256) void k_pre(const int* __restrict__ x,
                                             const void* __restrict__ tbl,
                                             const void* __restrict__ Wm,
                                             const void* __restrict__ bm,
                                             const void* __restrict__ headW,
                                             const void* __restrict__ W1,
                                             const void* __restrict__ W2,
                                             const int* __restrict__ flag,
                                             u16* __restrict__ emb,
                                             float* __restrict__ pre,
                                             u16* __restrict__ headWT,
                                             u16* __restrict__ W1T,
                                             u16* __restrict__ W2T) {
    __shared__ float smem[4160];     // embed: sWm[4096]+sbm[64]; transph: 64x65
    int isbf = *flag;
    int bid = blockIdx.x;
    int tid = threadIdx.x;

    if (bid < 128) {                 // ---- embed_pre role ----
        float* sWm = smem;
        float* sbm = smem + 4096;
        for (int i = tid; i < DD * DD; i += 256) sWm[i] = ldf(Wm, i, isbf);
        if (tid < DD) sbm[tid] = ldf(bm, tid, isbf);
        __syncthreads();

        int gi = bid * 256 + tid;
        int tok = gi >> 2, q = gi & 3;
        int id = x[tok];
        float e[DD];
        if (isbf) {
            const uint4* src = (const uint4*)((const u16*)tbl + id * DD);
            uint4* dst = (uint4*)(emb + tok * DD);
#pragma unroll
            for (int i = 0; i < 8; i++) {
                uint4 v = src[i];
                if ((i >> 1) == q) dst[i] = v;
                const u16* pu = (const u16*)&v;
#pragma unroll
                for (int j = 0; j < 8; j++) e[i * 8 + j] = bf2f(pu[j]);
            }
        } else {
            const float4* src = (const float4*)((const float*)tbl + id * DD);
            u16* dst = emb + tok * DD;
#pragma unroll
            for (int i = 0; i < 16; i++) {
                float4 v = src[i];
                e[i * 4 + 0] = v.x; e[i * 4 + 1] = v.y;
                e[i * 4 + 2] = v.z; e[i * 4 + 3] = v.w;
                if ((i >> 2) == q) {
                    u32 p0 = (u32)f2bf(v.x) | ((u32)f2bf(v.y) << 16);
                    u32 p1 = (u32)f2bf(v.z) | ((u32)f2bf(v.w) << 16);
                    ((u32*)dst)[i * 2] = p0;
                    ((u32*)dst)[i * 2 + 1] = p1;
                }
            }
        }
        int b = tok >> 10, t = tok & 1023;
        float* prow = pre + (t * BB + b) * DD + q * 16;
#pragma unroll
        for (int j4 = 0; j4 < 4; j4++) {
            int j0 = q * 16 + j4 * 4;
            float a0 = sbm[j0 + 0], a1 = sbm[j0 + 1];
            float a2 = sbm[j0 + 2], a3 = sbm[j0 + 3];
#pragma unroll
            for (int k = 0; k < DD; k++) {
                float ek = e[k];
                float4 wv = *(const float4*)&sWm[k * DD + j0];
                a0 += ek * wv.x; a1 += ek * wv.y;
                a2 += ek * wv.z; a3 += ek * wv.w;
            }
            ((float4*)prow)[j4] = make_float4(a0, a1, a2, a3);
        }
        return;
    }

    if (bid < 128 + 250) {           // ---- transph role ----
        float (*tile)[DD + 1] = (float(*)[DD + 1])smem;
        int v0 = (bid - 128) * 64;
        int c = tid & 63, rq = tid >> 6;
#pragma unroll
        for (int i = 0; i < 16; i++) {
            int k = i * 4 + rq;
            tile[k][c] = ldf(headW, k * VV + v0 + c, isbf);
        }
        __syncthreads();
#pragma unroll
        for (int i = 0; i < 16; i++) {
            int v = i * 4 + rq;
            headWT[(v0 + v) * DD + c] = f2bf(tile[c][v]);
        }
        return;
    }

    // ---- W1/W2 transpose role ----
    int idx = (bid - 378) * 256 + tid;
    if (idx < EE * DD * FF) {
        int e = idx >> 14, r = idx & 16383, d = r >> 8, f = r & 255;
        W1T[e * 16384 + f * DD + d] = f2bf(ldf(W1, idx, isbf));
    } else {
        int j2 = idx - EE * DD * FF;
        int e = j2 >> 14, r = j2 & 16383, f = r >> 6, d = r & 63;
        W2T[e * 16384 + d * FF + f] = f2bf(ldf(W2, j2, isbf));
    }
}

// ---------------------------------------------------------------------------
// K-MEGA: role-split pipeline stage.  Block layout (in order, roles present
// only when their chunk id >= 0):
//   scan  : BB blocks,   scan chunk scan_c   (t in [scan_c*CT, +CT))
//   ffn   : 256 blocks,  expert FFN for chunk ffn_c's tokens
//   gates : 8 blocks,    gates for chunk gates_c
//   ln    : 512 blocks,  layernorm for chunk ln_c
//   head  : 2016 blocks, head GEMM for chunk head_c
// Dynamic LDS: 33792 B when ffn present else 2048 B.
// ---------------------------------------------------------------------------
__global__ __launch_bounds__(256, 1) void k_mega(
        const float* __restrict__ pre, const void* __restrict__ Um,
        const u16* __restrict__ emb, const u16* __restrict__ W1T,
        const void* __restrict__ b1g, const u16* __restrict__ W2T,
        const void* __restrict__ b2g, const void* __restrict__ Wg,
        const void* __restrict__ bg, const void* __restrict__ ln_g,
        const void* __restrict__ ln_b, const u16* __restrict__ headWT,
        const void* __restrict__ head_b, const int* __restrict__ flag,
        float* __restrict__ mem, u16* __restrict__ eo,
        float* __restrict__ gates, u16* __restrict__ outb,
        void* __restrict__ logits,
        int scan_c, int ffn_c, int gates_c, int ln_c, int head_c) {
    extern __shared__ char dynsm[];
    int isbf = *flag;
    int bid = blockIdx.x;

    // ---------------- scan role ----------------
    if (scan_c >= 0) {
        if (bid < BB) {
            if (threadIdx.x >= 64) return;
            int b = bid, j = threadIdx.x;
            float* sm = (float*)dynsm;

            f32x2 c0, c1, c2, c3, c4, c5, c6, c7, c8, c9, c10, c11, c12, c13,
                  c14, c15, c16, c17, c18, c19, c20, c21, c22, c23, c24, c25,
                  c26, c27, c28, c29, c30, c31;
            if (isbf) {
                const u16* up = (const u16*)Um + j;
#define LDU(VAR, I) VAR = (f32x2){bf2f(up[(2 * I) * DD]), bf2f(up[(2 * I + 1) * DD])};
                LDU(c0, 0)  LDU(c1, 1)  LDU(c2, 2)  LDU(c3, 3)
                LDU(c4, 4)  LDU(c5, 5)  LDU(c6, 6)  LDU(c7, 7)
                LDU(c8, 8)  LDU(c9, 9)  LDU(c10, 10) LDU(c11, 11)
                LDU(c12, 12) LDU(c13, 13) LDU(c14, 14) LDU(c15, 15)
                LDU(c16, 16) LDU(c17, 17) LDU(c18, 18) LDU(c19, 19)
                LDU(c20, 20) LDU(c21, 21) LDU(c22, 22) LDU(c23, 23)
                LDU(c24, 24) LDU(c25, 25) LDU(c26, 26) LDU(c27, 27)
                LDU(c28, 28) LDU(c29, 29) LDU(c30, 30) LDU(c31, 31)
#undef LDU
            } else {
                const float* up = (const float*)Um + j;
#define LDU(VAR, I) VAR = (f32x2){up[(2 * I) * DD], up[(2 * I + 1) * DD]};
                LDU(c0, 0)  LDU(c1, 1)  LDU(c2, 2)  LDU(c3, 3)
                LDU(c4, 4)  LDU(c5, 5)  LDU(c6, 6)  LDU(c7, 7)
                LDU(c8, 8)  LDU(c9, 9)  LDU(c10, 10) LDU(c11, 11)
                LDU(c12, 12) LDU(c13, 13) LDU(c14, 14) LDU(c15, 15)
                LDU(c16, 16) LDU(c17, 17) LDU(c18, 18) LDU(c19, 19)
                LDU(c20, 20) LDU(c21, 21) LDU(c22, 22) LDU(c23, 23)
                LDU(c24, 24) LDU(c25, 25) LDU(c26, 26) LDU(c27, 27)
                LDU(c28, 28) LDU(c29, 29) LDU(c30, 30) LDU(c31, 31)
#undef LDU
            }
            // Force residency: opaque redefinition blocks remat-from-L2.
            asm volatile("" : "+v"(c0), "+v"(c1), "+v"(c2), "+v"(c3),
                              "+v"(c4), "+v"(c5), "+v"(c6), "+v"(c7));
            asm volatile("" : "+v"(c8), "+v"(c9), "+v"(c10), "+v"(c11),
                              "+v"(c12), "+v"(c13), "+v"(c14), "+v"(c15));
            asm volatile("" : "+v"(c16), "+v"(c17), "+v"(c18), "+v"(c19),
                              "+v"(c20), "+v"(c21), "+v"(c22), "+v"(c23));
            asm volatile("" : "+v"(c24), "+v"(c25), "+v"(c26), "+v"(c27),
                              "+v"(c28), "+v"(c29), "+v"(c30), "+v"(c31));

            int t0 = scan_c * CT, t1 = t0 + CT;
            sm[j] = (scan_c == 0) ? 0.f : mem[((t0 - 1) * BB + b) * DD + j];

            float pcur = pre[(t0 * BB + b) * DD + j];
            for (int t = t0; t < t1; t++) {
                int tn = (t + 1 < t1) ? t + 1 : t;
                float pnext = pre[(tn * BB + b) * DD + j];   // prefetch
                const f32x4* mv = (const f32x4*)sm;
                f32x2 A0 = {0.f, 0.f}, A1 = {0.f, 0.f};
                f32x2 A2 = {0.f, 0.f}, A3 = {0.f, 0.f};
#define STEP2(KK, UA, UB, UC, UD) {                             \
                f32x4 va = mv[2 * KK], vb = mv[2 * KK + 1];     \
                A0 += __builtin_shufflevector(va, va, 0, 1) * UA;   \
                A1 += __builtin_shufflevector(va, va, 2, 3) * UB;   \
                A2 += __builtin_shufflevector(vb, vb, 0, 1) * UC;   \
                A3 += __builtin_shufflevector(vb, vb, 2, 3) * UD; }
                STEP2(0, c0, c1, c2, c3)     STEP2(1, c4, c5, c6, c7)
                STEP2(2, c8, c9, c10, c11)   STEP2(3, c12, c13, c14, c15)
                STEP2(4, c16, c17, c18, c19) STEP2(5, c20, c21, c22, c23)
                STEP2(6, c24, c25, c26, c27) STEP2(7, c28, c29, c30, c31)
#undef STEP2
                float s = ((A0.x + A0.y) + (A1.x + A1.y))
                        + ((A2.x + A2.y) + (A3.x + A3.y)) + pcur;
                float ex = __expf(2.f * s);
                float mn = 1.f - 2.f * __builtin_amdgcn_rcpf(ex + 1.f);
                sm[j] = mn;     // single wave: DS in-order
                mem[(t * BB + b) * DD + j] = mn;
                pcur = pnext;
            }
            return;
        }
        bid -= BB;
    }

    // ---------------- ffn role (one time-chunk of tokens) ----------------
    if (ffn_c >= 0) {
        if (bid < 256) {
            int e = bid >> 5, lm = bid & 31;
            int mb = (lm >> 2) * 16 + ffn_c * 4 + (lm & 3);
            int w = threadIdx.x >> 6, l = threadIdx.x & 63;
            int lr = l & 15, lq = l >> 4;
            int m0 = mb * 64 + w * 16;
            u16* hw = (u16*)dynsm + w * (16 * 264);

            short8 a0 = ld8(emb + (m0 + lr) * DD + lq * 8);
            short8 a1 = ld8(emb + (m0 + lr) * DD + 32 + lq * 8);
            const u16* w1 = W1T + e * 16384;

            f32x4 acc[16];
#pragma unroll
            for (int nt = 0; nt < 16; nt++) {
                int n = nt * 16 + lr;
                short8 bf0 = ld8(w1 + n * DD + lq * 8);
                short8 bf1 = ld8(w1 + n * DD + 32 + lq * 8);
                f32x4 c = {0.f, 0.f, 0.f, 0.f};
                c = __builtin_amdgcn_mfma_f32_16x16x32_bf16(a0, bf0, c, 0, 0, 0);
                c = __builtin_amdgcn_mfma_f32_16x16x32_bf16(a1, bf1, c, 0, 0, 0);
                acc[nt] = c;
            }
#pragma unroll
            for (int nt = 0; nt < 16; nt++) {
                int n = nt * 16 + lr;
                float bb = ldf(b1g, e * FF + n, isbf);
#pragma unroll
                for (int r = 0; r < 4; r++) {
                    float xv = acc[nt][r] + bb;
                    float g = 0.5f * xv * (1.f + erff(xv * 0.70710678118654752f));
                    hw[(lq * 4 + r) * 264 + n] = f2bf(g);
                }
            }
            __syncthreads();

            f32x4 acc2[4];
#pragma unroll
            for (int dt = 0; dt < 4; dt++) acc2[dt] = (f32x4){0.f, 0.f, 0.f, 0.f};
            const u16* w2 = W2T + e * 16384;
#pragma unroll
            for (int kb = 0; kb < 8; kb++) {
                short8 af = ld8(hw + lr * 264 + kb * 32 + lq * 8);
#pragma unroll
                for (int dt = 0; dt < 4; dt++) {
                    short8 bf = ld8(w2 + (dt * 16 + lr) * FF + kb * 32 + lq * 8);
                    acc2[dt] = __builtin_amdgcn_mfma_f32_16x16x32_bf16(af, bf, acc2[dt], 0, 0, 0);
                }
            }
#pragma unroll
            for (int dt = 0; dt < 4; dt++) {
                int d = dt * 16 + lr;
                float bb = ldf(b2g, e * DD + d, isbf);
#pragma unroll
                for (int r = 0; r < 4; r++) {
                    int tok = m0 + lq * 4 + r;
                    eo[(tok * EE + e) * DD + d] = f2bf(acc2[dt][r] + bb);
                }
            }
            return;
        }
        bid -= 256;
    }

    // ---------------- gates role ----------------
    if (gates_c >= 0) {
        if (bid < 8) {
            float* sWg = (float*)dynsm;
            int tid = threadIdx.x;
            for (int i = tid; i < DD * EE; i += 256) sWg[i] = ldf(Wg, i, isbf);
            __syncthreads();

            int idx = bid * 256 + tid;          // [0,2048)
            int b = idx >> 8, toff = idx & 255;
            int t = gates_c * CT + toff;
            int tok = (b << 10) + t;
            const float* mr = mem + (t * BB + b) * DD;
            float z[EE];
#pragma unroll
            for (int e = 0; e < EE; e++) z[e] = ldf(bg, e, isbf);
            const float4* wg4 = (const float4*)sWg;
            const float4* mr4 = (const float4*)mr;
            for (int k4 = 0; k4 < 16; k4++) {
                float4 mv = mr4[k4];
                float m[4] = {mv.x, mv.y, mv.z, mv.w};
#pragma unroll
                for (int kk = 0; kk < 4; kk++) {
                    int k = k4 * 4 + kk;
                    float4 wa = wg4[k * 2], wb = wg4[k * 2 + 1];
                    z[0] += m[kk] * wa.x; z[1] += m[kk] * wa.y;
                    z[2] += m[kk] * wa.z; z[3] += m[kk] * wa.w;
                    z[4] += m[kk] * wb.x; z[5] += m[kk] * wb.y;
                    z[6] += m[kk] * wb.z; z[7] += m[kk] * wb.w;
                }
            }
            float zm = z[0];
#pragma unroll
            for (int e = 1; e < EE; e++) zm = fmaxf(zm, z[e]);
            float sum = 0.f;
#pragma unroll
            for (int e = 0; e < EE; e++) { z[e] = __expf(z[e] - zm); sum += z[e]; }
            float rs = __builtin_amdgcn_rcpf(sum);
#pragma unroll
            for (int e = 0; e < EE; e++) gates[tok * EE + e] = z[e] * rs;
            return;
        }
        bid -= 8;
    }

    // ---------------- ln role ----------------
    if (ln_c >= 0) {
        if (bid < 512) {
            int w = threadIdx.x >> 6, l = threadIdx.x & 63;
            int idx = bid * 4 + w;              // [0,2048)
            int b = idx >> 8, toff = idx & 255;
            int tok = (b << 10) + ln_c * CT + toff;
            const float* g = gates + tok * EE;
            const u16* er = eo + tok * EE * DD;
            float moe = 0.f;
#pragma unroll
            for (int e = 0; e < EE; e++) moe += g[e] * bf2f(er[e * DD + l]);
            float y = bf2f(emb[tok * DD + l]) + moe;
            float s = y;
#pragma unroll
            for (int off = 32; off > 0; off >>= 1) s += __shfl_xor(s, off, 64);
            float mu = s * (1.f / 64.f);
            float d = y - mu;
            float s2 = d * d;
#pragma unroll
            for (int off = 32; off > 0; off >>= 1) s2 += __shfl_xor(s2, off, 64);
            float var = s2 * (1.f / 64.f);
            float r = rsqrtf(var + 1e-5f);
            float o = ldf(ln_g, l, isbf) * d * r + ldf(ln_b, l, isbf);
            outb[tok * DD + l] = f2bf(o);
            return;
        }
        bid -= 512;
    }

    // ---------------- head role ----------------
    {
        int w = threadIdx.x >> 6, l = threadIdx.x & 63;
        int lr = l & 15, lq = l >> 4;
        int nb = bid / 32, lm = bid % 32;       // bid in [0,2016)
        int mb = (lm >> 2) * 16 + head_c * 4 + (lm & 3);
        int m0 = mb * 64 + w * 16;
        int n0 = nb * 256;
        int ntc = (nb == 62) ? 8 : 16;

        short8 a0 = ld8(outb + (m0 + lr) * DD + lq * 8);
        short8 a1 = ld8(outb + (m0 + lr) * DD + 32 + lq * 8);

        for (int nt = 0; nt < ntc; nt++) {
            int n = n0 + nt * 16 + lr;
            short8 bf0 = ld8(headWT + n * DD + lq * 8);
            short8 bf1 = ld8(headWT + n * DD + 32 + lq * 8);
            f32x4 c = {0.f, 0.f, 0.f, 0.f};
            c = __builtin_amdgcn_mfma_f32_16x16x32_bf16(a0, bf0, c, 0, 0, 0);
            c = __builtin_amdgcn_mfma_f32_16x16x32_bf16(a1, bf1, c, 0, 0, 0);
            float hb = ldf(head_b, n, isbf);
            if (isbf) {
#pragma unroll
                for (int r = 0; r < 4; r++)
                    ((u16*)logits)[(m0 + lq * 4 + r) * VV + n] = f2bf(c[r] + hb);
            } else {
#pragma unroll
                for (int r = 0; r < 4; r++)
                    ((float*)logits)[(m0 + lq * 4 + r) * VV + n] = c[r] + hb;
            }
        }
    }
}

// ---------------------------------------------------------------------------
extern "C" void kernel_launch(void* const* d_in, const int* in_sizes, int n_in,
                              void* d_out, int out_size, void* d_ws, size_t ws_size,
                              hipStream_t stream) {
    const int*  x      = (const int*)d_in[0];
    const void* tbl    = d_in[1];
    const void* Wm     = d_in[2];
    const void* Um     = d_in[3];
    const void* bm     = d_in[4];
    const void* Wg     = d_in[5];
    const void* bg     = d_in[6];
    const void* W1     = d_in[7];
    const void* b1     = d_in[8];
    const void* W2     = d_in[9];
    const void* b2     = d_in[10];
    const void* ln_g   = d_in[11];
    const void* ln_b   = d_in[12];
    const void* headW  = d_in[13];
    const void* head_b = d_in[14];

    char* w = (char*)d_ws;
    int*   flag   = (int*)(w);                    // 256 B
    u16*   headWT = (u16*)(w + 0x0000100);        // 2,048,000 B
    u16*   W1T    = (u16*)(w + 0x0200000);        //   262,144 B
    u16*   W2T    = (u16*)(w + 0x0240000);        //   262,144 B
    u16*   emb    = (u16*)(w + 0x0280000);        // 1,048,576 B
    u16*   outb   = (u16*)(w + 0x0380000);        // 1,048,576 B
    float* pre    = (float*)(w + 0x0480000);      // 2,097,152 B
    float* mem    = (float*)(w + 0x0680000);      // 2,097,152 B
    float* gates  = (float*)(w + 0x0880000);      //   262,144 B
    u16*   eo     = (u16*)(w + 0x08C0000);        // 8,388,608 B  (end 17.6 MB)

    k_sniff<<<dim3(1), dim3(256), 0, stream>>>((const u32*)tbl, flag);
    k_pre<<<dim3(1402), dim3(256), 0, stream>>>(x, tbl, Wm, bm, headW, W1, W2,
                                                flag, emb, pre, headWT, W1T, W2T);

    auto mega = [&](int sc, int fc, int gc, int lc, int hc) {
        int grid = 0;
        if (sc >= 0) grid += BB;
        if (fc >= 0) grid += 256;
        if (gc >= 0) grid += 8;
        if (lc >= 0) grid += 512;
        if (hc >= 0) grid += 2016;
        size_t sh = (fc >= 0) ? (size_t)(4 * 16 * 264 * 2) : (size_t)2048;
        k_mega<<<dim3(grid), dim3(256), sh, stream>>>(
            pre, Um, emb, W1T, b1, W2T, b2, Wg, bg, ln_g, ln_b, headWT, head_b,
            flag, mem, eo, gates, outb, d_out, sc, fc, gc, lc, hc);
    };

    mega(0, 0, -1, -1, -1);
    mega(1, 1, 0, -1, -1);
    mega(2, 2, 1, 0, -1);
    mega(3, 3, 2, 1, 0);
    mega(-1, -1, 3, 2, 1);
    mega(-1, -1, -1, 3, 2);
    mega(-1, -1, -1, -1, 3);
}